// Round 9
// baseline (259.328 us; speedup 1.0000x reference)
//
#include <hip/hip_runtime.h>

typedef unsigned short u16;
typedef unsigned int u32;
typedef __attribute__((ext_vector_type(4))) float f32x4;
typedef __attribute__((ext_vector_type(8))) __bf16 bf16x8;

#define T_SEQ 2048
#define DMODEL 1024
#define NHEAD 16
#define HEADS 64
#define FFDIM 4096
#define MNQ 2097152l  // 2048*1024

__device__ __forceinline__ u16 f2bf(float f) {
  u32 u = __builtin_bit_cast(u32, f);
  u = u + 0x7FFFu + ((u >> 16) & 1u);
  return (u16)(u >> 16);
}
__device__ __forceinline__ float bf2f(u16 h) {
  u32 u = ((u32)h) << 16;
  return __builtin_bit_cast(float, u);
}
__device__ __forceinline__ void gload_lds16(const u16* g, u16* l) {
  __builtin_amdgcn_global_load_lds(
      (const __attribute__((address_space(1))) u32*)g,
      (__attribute__((address_space(3))) u32*)l, 16, 0, 0);
}

// ------------- prep: ALL weight transposes + RMSNorm1 in one launch ----------
__global__ __launch_bounds__(256) void prep_k(
    const float* __restrict__ Wq, const float* __restrict__ Wk,
    const float* __restrict__ Wv, const float* __restrict__ Wproj,
    const float* __restrict__ W1, const float* __restrict__ W2,
    const float* __restrict__ x, const float* __restrict__ g1,
    u16* __restrict__ QKVwT, u16* __restrict__ WprojT,
    u16* __restrict__ W1T, u16* __restrict__ W2T, u16* __restrict__ xn1) {
  __shared__ u16 tile[64 * 66];
  __shared__ float wsum[4];
  int bid = blockIdx.x;
  int tid = threadIdx.x;
  if (bid >= 3072) {
    int row = bid - 3072;
    const float4* xr = (const float4*)(x + (long)row * DMODEL);
    float4 v = xr[tid];
    float ss = v.x * v.x + v.y * v.y + v.z * v.z + v.w * v.w;
#pragma unroll
    for (int off = 32; off >= 1; off >>= 1) ss += __shfl_xor(ss, off, 64);
    if ((tid & 63) == 0) wsum[tid >> 6] = ss;
    __syncthreads();
    float tot = wsum[0] + wsum[1] + wsum[2] + wsum[3];
    float rms = rsqrtf(tot * (1.0f / DMODEL) + 1e-6f);
    float4 gv = ((const float4*)g1)[tid];
    ushort4 o4 = make_ushort4(f2bf(v.x * rms * gv.x), f2bf(v.y * rms * gv.y),
                              f2bf(v.z * rms * gv.z), f2bf(v.w * rms * gv.w));
    ((ushort4*)(xn1 + (long)row * DMODEL))[tid] = o4;
    return;
  }
  const float* in;
  u16* out;
  long ldin, ldout;
  int r0, c0;
  if (bid < 768) {
    int z = bid >> 4, xi = bid & 15;
    int wsel = z >> 4, h = z & 15;
    in = (wsel == 0 ? Wq : (wsel == 1 ? Wk : Wv)) + (long)h * 65536;
    out = QKVwT + (long)wsel * 1048576 + (long)h * 65536;
    ldin = 64; ldout = 1024;
    r0 = xi * 64; c0 = 0;
  } else if (bid < 1024) {
    int b = bid - 768;
    in = Wproj; out = WprojT; ldin = 1024; ldout = 1024;
    r0 = (b >> 4) * 64; c0 = (b & 15) * 64;
  } else if (bid < 2048) {
    int b = bid - 1024;
    in = W1; out = W1T; ldin = 4096; ldout = 1024;
    r0 = (b & 15) * 64; c0 = (b >> 4) * 64;
  } else {
    int b = bid - 2048;
    in = W2; out = W2T; ldin = 1024; ldout = 4096;
    r0 = (b >> 4) * 64; c0 = (b & 15) * 64;
  }
#pragma unroll
  for (int p = 0; p < 16; ++p) {
    int idx = p * 256 + tid;
    int r = idx >> 6, c = idx & 63;
    tile[c * 66 + r] = f2bf(in[(long)(r0 + r) * ldin + c0 + c]);
  }
  __syncthreads();
#pragma unroll
  for (int p = 0; p < 16; ++p) {
    int idx = p * 256 + tid;
    int c = idx >> 6, r = idx & 63;
    out[(long)(c0 + c) * ldout + r0 + r] = tile[c * 66 + r];
  }
}

// ---- fused: proj split-K(x2, bf16 partials) reduce -> x1, RMSNorm -> xn2 ----
__global__ __launch_bounds__(256) void proj_rms_k(
    const u16* __restrict__ part, const float* __restrict__ bias,
    const float* __restrict__ resid, const float* __restrict__ g,
    float* __restrict__ x1, u16* __restrict__ xn2) {
  int row = blockIdx.x;
  int tid = threadIdx.x;
  long i = (long)row * DMODEL + tid * 4;
  float4 r = *(const float4*)(resid + i);
  float4 bi = *(const float4*)(bias + tid * 4);
  float4 v;
  v.x = r.x + bi.x; v.y = r.y + bi.y; v.z = r.z + bi.z; v.w = r.w + bi.w;
#pragma unroll
  for (int z = 0; z < 2; ++z) {
    ushort4 a = *(const ushort4*)(part + z * MNQ + i);
    v.x += bf2f(a.x); v.y += bf2f(a.y); v.z += bf2f(a.z); v.w += bf2f(a.w);
  }
  *(float4*)(x1 + i) = v;
  float ss = v.x * v.x + v.y * v.y + v.z * v.z + v.w * v.w;
#pragma unroll
  for (int off = 32; off >= 1; off >>= 1) ss += __shfl_xor(ss, off, 64);
  __shared__ float wsum[4];
  if ((tid & 63) == 0) wsum[tid >> 6] = ss;
  __syncthreads();
  float tot = wsum[0] + wsum[1] + wsum[2] + wsum[3];
  float rms = rsqrtf(tot * (1.0f / DMODEL) + 1e-6f);
  float4 gv = ((const float4*)g)[tid];
  ushort4 o4 = make_ushort4(f2bf(v.x * rms * gv.x), f2bf(v.y * rms * gv.y),
                            f2bf(v.z * rms * gv.z), f2bf(v.w * rms * gv.w));
  ((ushort4*)(xn2 + (long)row * DMODEL))[tid] = o4;
}

// ---------------- GEMM: C[M,N] = A[M,K] * Bt[N,K]^T, bf16 in, fp32 acc ------
// 128x128 tile (4 waves, wave-tile 64x64, 16 MFMA per 8 ds_read_b128 per iter),
// 3-stage global_load_lds pipeline, s_waitcnt vmcnt(4) + raw s_barrier (queue
// never drained mid-loop). 48 KB LDS -> 3 blocks/CU.
// EPI 0: bf16 (+V-transpose for cols>=2048). 2: silu->bf16. 4: bf16 partial.
template <int EPI>
__global__ __launch_bounds__(256, 3) void gemm_bt_k(
    const u16* __restrict__ A, const u16* __restrict__ Bt, int N, int K, int kc,
    u16* __restrict__ out16, u16* __restrict__ vt, u16* __restrict__ part) {
  __shared__ __align__(16) u16 As[3][128 * 32];
  __shared__ __align__(16) u16 Bs[3][128 * 32];
  int tid = threadIdx.x;
  int w = tid >> 6, lane = tid & 63;
  int quad = lane >> 4, l15 = lane & 15;
  int m0 = blockIdx.x * 128, n0 = blockIdx.y * 128;
  int kz = blockIdx.z;
  int wr = w >> 1, wc = w & 1;

  f32x4 acc[4][4] = {};

  int lr = lane >> 2, lc = (lane & 3) * 8;
  const u16* Ak = A + (long)(m0 + w * 32 + lr) * K + lc + (long)kz * kc;
  const u16* A2k = Ak + (long)16 * K;
  const u16* Bk = Bt + (long)(n0 + w * 32 + lr) * K + lc + (long)kz * kc;
  const u16* B2k = Bk + (long)16 * K;
  u16* Aw[3] = {As[0] + w * 1024, As[1] + w * 1024, As[2] + w * 1024};
  u16* Bw[3] = {Bs[0] + w * 1024, Bs[1] + w * 1024, Bs[2] + w * 1024};

  int niter = kc >> 5;

  // prologue: issue tiles 0 and 1 (4 loads per tile per thread)
  gload_lds16(Ak, Aw[0]);
  gload_lds16(A2k, Aw[0] + 512);
  gload_lds16(Bk, Bw[0]);
  gload_lds16(B2k, Bw[0] + 512);
  gload_lds16(Ak + 32, Aw[1]);
  gload_lds16(A2k + 32, Aw[1] + 512);
  gload_lds16(Bk + 32, Bw[1]);
  gload_lds16(B2k + 32, Bw[1] + 512);

  int cb = 0;
  for (int k = 0; k < niter; ++k) {
    if (k + 2 < niter) {
      // tile k's 4 loads (oldest) must land; tile k+1's 4 stay in flight
      asm volatile("s_waitcnt vmcnt(4)\n\ts_barrier" ::: "memory");
      int pb = (cb == 0) ? 2 : cb - 1;  // (k+2)%3 — freed at iter k-1
      int off = (k + 2) * 32;
      gload_lds16(Ak + off, Aw[pb]);
      gload_lds16(A2k + off, Aw[pb] + 512);
      gload_lds16(Bk + off, Bw[pb]);
      gload_lds16(B2k + off, Bw[pb] + 512);
    } else {
      asm volatile("s_waitcnt vmcnt(0)\n\ts_barrier" ::: "memory");
    }
    const u16* Ab = As[cb];
    const u16* Bb = Bs[cb];
    bf16x8 af[4], bfr[4];
#pragma unroll
    for (int mt = 0; mt < 4; ++mt)
      af[mt] = *(const bf16x8*)(Ab + (wr * 64 + mt * 16 + l15) * 32 + quad * 8);
#pragma unroll
    for (int nt = 0; nt < 4; ++nt)
      bfr[nt] = *(const bf16x8*)(Bb + (wc * 64 + nt * 16 + l15) * 32 + quad * 8);
#pragma unroll
    for (int mt = 0; mt < 4; ++mt)
#pragma unroll
      for (int nt = 0; nt < 4; ++nt)
        acc[mt][nt] = __builtin_amdgcn_mfma_f32_16x16x32_bf16(
            af[mt], bfr[nt], acc[mt][nt], 0, 0, 0);
    cb = (cb == 2) ? 0 : cb + 1;
  }

  bool vblock = (EPI == 0) && (vt != nullptr) && (n0 >= 2048);
  u16* pb = nullptr;
  if (EPI == 4) pb = part + (long)kz * MNQ;
#pragma unroll
  for (int mt = 0; mt < 4; ++mt)
#pragma unroll
    for (int nt = 0; nt < 4; ++nt) {
      int col = n0 + wc * 64 + nt * 16 + l15;
      if (EPI == 0 && vblock) {
        int s = col - 2048;
        int row0 = m0 + wr * 64 + mt * 16 + quad * 4;
        ushort4 pk = make_ushort4(f2bf(acc[mt][nt][0]), f2bf(acc[mt][nt][1]),
                                  f2bf(acc[mt][nt][2]), f2bf(acc[mt][nt][3]));
        *(ushort4*)(vt + (long)s * 2048 + row0) = pk;
        continue;
      }
#pragma unroll
      for (int r = 0; r < 4; ++r) {
        int row = m0 + wr * 64 + mt * 16 + quad * 4 + r;
        long idx = (long)row * N + col;
        float v = acc[mt][nt][r];
        if (EPI == 0) {
          out16[idx] = f2bf(v);
        } else if (EPI == 2) {
          out16[idx] = f2bf(v / (1.0f + __expf(-v)));
        } else if (EPI == 4) {
          pb[idx] = f2bf(v);
        }
      }
    }
}

// ---------------- FFN2 split-K reduce (bf16 partials) ----------------
__global__ __launch_bounds__(256) void reduce_ffn2_k(
    const u16* __restrict__ part, const float* __restrict__ resid,
    float* __restrict__ out) {
  long i = ((long)blockIdx.x * 256 + threadIdx.x) * 4;
  float4 r = *(const float4*)(resid + i);
  float4 o = r;
#pragma unroll
  for (int z = 0; z < 4; ++z) {
    ushort4 a = *(const ushort4*)(part + z * MNQ + i);
    o.x += bf2f(a.x); o.y += bf2f(a.y); o.z += bf2f(a.z); o.w += bf2f(a.w);
  }
  *(float4*)(out + i) = o;
}

// ------- split-KV flash attention, S^T trick (no per-elem P transpose) -------
#define LSTR 72
__global__ __launch_bounds__(256) void attn_part_k(const u16* __restrict__ QKV,
                                                   const u16* __restrict__ Vt,
                                                   u16* __restrict__ Opart,
                                                   float* __restrict__ lpart) {
  __shared__ __align__(16) u16 Qs[64 * LSTR];  // aliased as P after aq read
  __shared__ __align__(16) u16 Ks[64 * LSTR];
  __shared__ __align__(16) u16 Vs[64 * LSTR];
  __shared__ float lbuf[64];

  int tid = threadIdx.x;
  int w = tid >> 6, lane = tid & 63;
  int quad = lane >> 4, l15 = lane & 15;
  int h = blockIdx.y;

  int p = blockIdx.x;
  int bx = 0, acc0 = 0;
  while (true) {
    int n = (bx >> 3) + 1;
    if (p < acc0 + n) break;
    acc0 += n;
    ++bx;
  }
  int c = p - acc0;
  int t0 = bx * 64;
  int jstart = c * 8;
  int jend = min(jstart + 8, bx + 1);

#pragma unroll
  for (int pp = 0; pp < 2; ++pp) {
    int idx = pp * 256 + tid;
    int row = idx >> 3, cc = idx & 7;
    *(uint4*)(Qs + row * LSTR + cc * 8) =
        *(const uint4*)(QKV + (long)(t0 + row) * 3072 + h * 64 + cc * 8);
  }
  __syncthreads();
  bf16x8 aq[2];
#pragma unroll
  for (int ks = 0; ks < 2; ++ks)
    aq[ks] = *(const bf16x8*)(Qs + (w * 16 + l15) * LSTR + ks * 32 + quad * 8);

  f32x4 oacc[4] = {};
  float lsum = 0.f;
  int qg = t0 + w * 16 + l15;  // this lane's q for S^T columns

  u16* PsW = Qs + w * (16 * LSTR);

  for (int j = jstart; j < jend; ++j) {
    __syncthreads();
#pragma unroll
    for (int pp = 0; pp < 2; ++pp) {
      int idx = pp * 256 + tid;
      int row = idx >> 3, cc = idx & 7;
      *(uint4*)(Ks + row * LSTR + cc * 8) =
          *(const uint4*)(QKV + (long)(j * 64 + row) * 3072 + 1024 + h * 64 + cc * 8);
      *(uint4*)(Vs + row * LSTR + cc * 8) =
          *(const uint4*)(Vt + (long)h * (64 * 2048) + (long)row * 2048 + j * 64 + cc * 8);
    }
    __syncthreads();

    // S^T[u][q]: A=K (m=u), B=Q (n=q)
    f32x4 sacc[4] = {};
#pragma unroll
    for (int ks = 0; ks < 2; ++ks)
#pragma unroll
      for (int ut = 0; ut < 4; ++ut) {
        bf16x8 kf = *(const bf16x8*)(Ks + (ut * 16 + l15) * LSTR + ks * 32 + quad * 8);
        sacc[ut] = __builtin_amdgcn_mfma_f32_16x16x32_bf16(kf, aq[ks], sacc[ut], 0, 0, 0);
      }

    bool boundary = (j == bx);
#pragma unroll
    for (int ut = 0; ut < 4; ++ut) {
      float pv[4];
#pragma unroll
      for (int r = 0; r < 4; ++r) {
        float v = exp2f(sacc[ut][r] * 0.18033688f);
        if (boundary) {
          int u = j * 64 + ut * 16 + quad * 4 + r;
          if (u > qg) v = 0.f;
        }
        pv[r] = v;
        lsum += v;
      }
      ushort4 pk = make_ushort4(f2bf(pv[0]), f2bf(pv[1]), f2bf(pv[2]), f2bf(pv[3]));
      *(ushort4*)(PsW + l15 * LSTR + ut * 16 + quad * 4) = pk;
    }
    asm volatile("s_waitcnt lgkmcnt(0)" ::: "memory");
    // PV: A=P[q][u] (rows q=l15), B=V^T[d][u]
#pragma unroll
    for (int ks = 0; ks < 2; ++ks) {
      bf16x8 pf = *(const bf16x8*)(PsW + l15 * LSTR + ks * 32 + quad * 8);
#pragma unroll
      for (int ct = 0; ct < 4; ++ct) {
        bf16x8 vf = *(const bf16x8*)(Vs + (ct * 16 + l15) * LSTR + ks * 32 + quad * 8);
        oacc[ct] = __builtin_amdgcn_mfma_f32_16x16x32_bf16(pf, vf, oacc[ct], 0, 0, 0);
      }
    }
  }

  // full l(q=w*16+l15): sum over the 4 quads
  lsum += __shfl_xor(lsum, 16, 64);
  lsum += __shfl_xor(lsum, 32, 64);
  if (quad == 0) lbuf[w * 16 + l15] = 1.0f / lsum;
  asm volatile("s_waitcnt lgkmcnt(0)" ::: "memory");

  long slot = (long)p * 16 + h;
  float inv[4];
#pragma unroll
  for (int r = 0; r < 4; ++r) inv[r] = lbuf[w * 16 + quad * 4 + r];
  u16* Ob = Opart + slot * 4096;
#pragma unroll
  for (int ct = 0; ct < 4; ++ct)
#pragma unroll
    for (int r = 0; r < 4; ++r)
      Ob[(w * 16 + quad * 4 + r) * 64 + ct * 16 + l15] = f2bf(oacc[ct][r] * inv[r]);
  if (quad == 0) lpart[slot * 64 + w * 16 + l15] = lsum;
}

// ---------------- combine partials (exact: sum O_c / sum l_c) ----------------
__global__ __launch_bounds__(256) void attn_combine_k(
    const u16* __restrict__ Opart, const float* __restrict__ lpart,
    u16* __restrict__ out) {
  int bx = blockIdx.x, h = blockIdx.y;
  int g = bx >> 3;
  int p0 = 4 * g * (g + 1) + (bx - 8 * g) * (g + 1);
  int nc = g + 1;
  int tid = threadIdx.x;
  int row = tid >> 2, c4 = (tid & 3) * 16;

  float lv[4];
  float wsum = 0.f;
  for (int cidx = 0; cidx < nc; ++cidx) {
    long slot = (long)(p0 + cidx) * 16 + h;
    lv[cidx] = lpart[slot * 64 + row];
    wsum += lv[cidx];
  }
  float rinv = 1.0f / wsum;

  float o[16];
#pragma unroll
  for (int i = 0; i < 16; ++i) o[i] = 0.f;
  for (int cidx = 0; cidx < nc; ++cidx) {
    float wc = lv[cidx] * rinv;
    const u16* Ob = Opart + ((long)(p0 + cidx) * 16 + h) * 4096 + row * 64 + c4;
    bf16x8 a = *(const bf16x8*)Ob;
    bf16x8 b = *(const bf16x8*)(Ob + 8);
#pragma unroll
    for (int i = 0; i < 8; ++i) {
      o[i] += wc * (float)a[i];
      o[8 + i] += wc * (float)b[i];
    }
  }
  u16 ob[16];
#pragma unroll
  for (int i = 0; i < 16; ++i) ob[i] = f2bf(o[i]);
  u16* op = out + (long)(bx * 64 + row) * 1024 + h * 64 + c4;
  *(uint4*)op = *(uint4*)ob;
  *(uint4*)(op + 8) = *(uint4*)(ob + 8);
}

// ---------------- launch ----------------
extern "C" void kernel_launch(void* const* d_in, const int* in_sizes, int n_in,
                              void* d_out, int out_size, void* d_ws, size_t ws_size,
                              hipStream_t stream) {
  const float* x     = (const float*)d_in[0];
  const float* Wq    = (const float*)d_in[1];
  const float* Wk    = (const float*)d_in[2];
  const float* Wv    = (const float*)d_in[3];
  const float* Wproj = (const float*)d_in[4];
  const float* bproj = (const float*)d_in[5];
  const float* W1    = (const float*)d_in[6];
  const float* W2    = (const float*)d_in[7];
  const float* g1    = (const float*)d_in[8];
  const float* g2    = (const float*)d_in[9];

  char* ws = (char*)d_ws;
  u16* QKVwT  = (u16*)(ws);                   // 0..6 MiB
  u16* WprojT = (u16*)(ws + (6ul << 20));     // 6..8
  u16* W1T    = (u16*)(ws + (8ul << 20));     // 8..16
  u16* W2T    = (u16*)(ws + (16ul << 20));    // 16..24 (live thru FFN2)
  u16* xn1    = (u16*)(ws + (24ul << 20));    // 24..28
  u16* QKVb   = (u16*)(ws + (28ul << 20));    // 28..40
  u16* VtB    = (u16*)(ws + (40ul << 20));    // 40..44
  u16* attn   = (u16*)(ws + (44ul << 20));    // 44..48
  float* x1   = (float*)(ws + (48ul << 20));  // 48..56
  u16* xn2    = (u16*)(ws + (56ul << 20));    // 56..60
  u16* hbuf   = (u16*)(ws + (60ul << 20));    // 60..76
  // aliases (dead-region reuse):
  u16* Opart    = (u16*)(ws + (48ul << 20));  // 48..58 (dead before proj_rms)
  float* lpart  = (float*)(ws + (58ul << 20));// 58..58.4
  u16* projp    = (u16*)(ws + (28ul << 20));  // 28..36: 2 x 4 MiB bf16 partials
  u16* ffn2p    = (u16*)(ws + (28ul << 20));  // 28..44 (projp dead by then)
  if (ws_size < (76ul << 20)) return;

  dim3 blk(256);

  prep_k<<<dim3(5120), blk, 0, stream>>>(
      Wq, Wk, Wv, Wproj, W1, W2, x, g1, QKVwT, WprojT, W1T, W2T, xn1);
  gemm_bt_k<0><<<dim3(16, 24, 1), blk, 0, stream>>>(
      xn1, QKVwT, 3072, 1024, 1024, QKVb, VtB, nullptr);
  attn_part_k<<<dim3(80, 16), blk, 0, stream>>>(QKVb, VtB, Opart, lpart);
  attn_combine_k<<<dim3(32, 16), blk, 0, stream>>>(Opart, lpart, attn);
  // proj: split-K x2 (K=1024 -> 2x512), grid 256 blocks, bf16 partials
  gemm_bt_k<4><<<dim3(16, 8, 2), blk, 0, stream>>>(
      attn, WprojT, 1024, 1024, 512, nullptr, nullptr, projp);
  proj_rms_k<<<dim3(2048), blk, 0, stream>>>(projp, bproj, x, g2, x1, xn2);
  gemm_bt_k<2><<<dim3(16, 32, 1), blk, 0, stream>>>(
      xn2, W1T, 4096, 1024, 1024, hbuf, nullptr, nullptr);
  // FFN2: split-K x4 (K=4096 -> 4x1024), grid 512 blocks, bf16 partials
  gemm_bt_k<4><<<dim3(16, 8, 4), blk, 0, stream>>>(
      hbuf, W2T, 1024, 4096, 1024, nullptr, nullptr, ffn2p);
  reduce_ffn2_k<<<dim3(2048), blk, 0, stream>>>(ffn2p, x1, (float*)d_out);
}

// Round 10
// 254.945 us; speedup vs baseline: 1.0172x; 1.0172x over previous
//
#include <hip/hip_runtime.h>

typedef unsigned short u16;
typedef unsigned int u32;
typedef __attribute__((ext_vector_type(4))) float f32x4;
typedef __attribute__((ext_vector_type(8))) __bf16 bf16x8;

#define T_SEQ 2048
#define DMODEL 1024
#define NHEAD 16
#define HEADS 64
#define FFDIM 4096
#define MNQ 2097152l  // 2048*1024

__device__ __forceinline__ u16 f2bf(float f) {
  u32 u = __builtin_bit_cast(u32, f);
  u = u + 0x7FFFu + ((u >> 16) & 1u);
  return (u16)(u >> 16);
}
__device__ __forceinline__ float bf2f(u16 h) {
  u32 u = ((u32)h) << 16;
  return __builtin_bit_cast(float, u);
}
__device__ __forceinline__ void gload_lds16(const u16* g, u16* l) {
  __builtin_amdgcn_global_load_lds(
      (const __attribute__((address_space(1))) u32*)g,
      (__attribute__((address_space(3))) u32*)l, 16, 0, 0);
}

// ------------- prep: ALL weight transposes + RMSNorm1 in one launch ----------
__global__ __launch_bounds__(256) void prep_k(
    const float* __restrict__ Wq, const float* __restrict__ Wk,
    const float* __restrict__ Wv, const float* __restrict__ Wproj,
    const float* __restrict__ W1, const float* __restrict__ W2,
    const float* __restrict__ x, const float* __restrict__ g1,
    u16* __restrict__ QKVwT, u16* __restrict__ WprojT,
    u16* __restrict__ W1T, u16* __restrict__ W2T, u16* __restrict__ xn1) {
  __shared__ u16 tile[64 * 66];
  __shared__ float wsum[4];
  int bid = blockIdx.x;
  int tid = threadIdx.x;
  if (bid >= 3072) {
    int row = bid - 3072;
    const float4* xr = (const float4*)(x + (long)row * DMODEL);
    float4 v = xr[tid];
    float ss = v.x * v.x + v.y * v.y + v.z * v.z + v.w * v.w;
#pragma unroll
    for (int off = 32; off >= 1; off >>= 1) ss += __shfl_xor(ss, off, 64);
    if ((tid & 63) == 0) wsum[tid >> 6] = ss;
    __syncthreads();
    float tot = wsum[0] + wsum[1] + wsum[2] + wsum[3];
    float rms = rsqrtf(tot * (1.0f / DMODEL) + 1e-6f);
    float4 gv = ((const float4*)g1)[tid];
    ushort4 o4 = make_ushort4(f2bf(v.x * rms * gv.x), f2bf(v.y * rms * gv.y),
                              f2bf(v.z * rms * gv.z), f2bf(v.w * rms * gv.w));
    ((ushort4*)(xn1 + (long)row * DMODEL))[tid] = o4;
    return;
  }
  const float* in;
  u16* out;
  long ldin, ldout;
  int r0, c0;
  if (bid < 768) {
    int z = bid >> 4, xi = bid & 15;
    int wsel = z >> 4, h = z & 15;
    in = (wsel == 0 ? Wq : (wsel == 1 ? Wk : Wv)) + (long)h * 65536;
    out = QKVwT + (long)wsel * 1048576 + (long)h * 65536;
    ldin = 64; ldout = 1024;
    r0 = xi * 64; c0 = 0;
  } else if (bid < 1024) {
    int b = bid - 768;
    in = Wproj; out = WprojT; ldin = 1024; ldout = 1024;
    r0 = (b >> 4) * 64; c0 = (b & 15) * 64;
  } else if (bid < 2048) {
    int b = bid - 1024;
    in = W1; out = W1T; ldin = 4096; ldout = 1024;
    r0 = (b & 15) * 64; c0 = (b >> 4) * 64;
  } else {
    int b = bid - 2048;
    in = W2; out = W2T; ldin = 1024; ldout = 4096;
    r0 = (b >> 4) * 64; c0 = (b & 15) * 64;
  }
#pragma unroll
  for (int p = 0; p < 16; ++p) {
    int idx = p * 256 + tid;
    int r = idx >> 6, c = idx & 63;
    tile[c * 66 + r] = f2bf(in[(long)(r0 + r) * ldin + c0 + c]);
  }
  __syncthreads();
#pragma unroll
  for (int p = 0; p < 16; ++p) {
    int idx = p * 256 + tid;
    int c = idx >> 6, r = idx & 63;
    out[(long)(c0 + c) * ldout + r0 + r] = tile[c * 66 + r];
  }
}

// ---- fused: proj split-K(x2, bf16 partials) reduce -> x1, RMSNorm -> xn2 ----
__global__ __launch_bounds__(256) void proj_rms_k(
    const u16* __restrict__ part, const float* __restrict__ bias,
    const float* __restrict__ resid, const float* __restrict__ g,
    float* __restrict__ x1, u16* __restrict__ xn2) {
  int row = blockIdx.x;
  int tid = threadIdx.x;
  long i = (long)row * DMODEL + tid * 4;
  float4 r = *(const float4*)(resid + i);
  float4 bi = *(const float4*)(bias + tid * 4);
  float4 v;
  v.x = r.x + bi.x; v.y = r.y + bi.y; v.z = r.z + bi.z; v.w = r.w + bi.w;
#pragma unroll
  for (int z = 0; z < 2; ++z) {
    ushort4 a = *(const ushort4*)(part + z * MNQ + i);
    v.x += bf2f(a.x); v.y += bf2f(a.y); v.z += bf2f(a.z); v.w += bf2f(a.w);
  }
  *(float4*)(x1 + i) = v;
  float ss = v.x * v.x + v.y * v.y + v.z * v.z + v.w * v.w;
#pragma unroll
  for (int off = 32; off >= 1; off >>= 1) ss += __shfl_xor(ss, off, 64);
  __shared__ float wsum[4];
  if ((tid & 63) == 0) wsum[tid >> 6] = ss;
  __syncthreads();
  float tot = wsum[0] + wsum[1] + wsum[2] + wsum[3];
  float rms = rsqrtf(tot * (1.0f / DMODEL) + 1e-6f);
  float4 gv = ((const float4*)g)[tid];
  ushort4 o4 = make_ushort4(f2bf(v.x * rms * gv.x), f2bf(v.y * rms * gv.y),
                            f2bf(v.z * rms * gv.z), f2bf(v.w * rms * gv.w));
  ((ushort4*)(xn2 + (long)row * DMODEL))[tid] = o4;
}

// ---------------- GEMM: C[M,N] = A[M,K] * Bt[N,K]^T, bf16 in, fp32 acc ------
// 128x128 tile, 3-stage global_load_lds pipeline (vmcnt(4) + raw s_barrier).
// XCD-aware 1-D grid swizzle: xcd = bid&7 (dispatch heuristic). MODE 0:
// partition n across XCDs (B-slice resident in that XCD's L2); MODE 1:
// partition m (A-slice resident). nm is always 16 (M=2048).
// EPI 0: bf16 (+V-transpose for cols>=2048). 2: silu->bf16. 4: bf16 partial.
template <int EPI, int MODE>
__global__ __launch_bounds__(256, 3) void gemm_bt_k(
    const u16* __restrict__ A, const u16* __restrict__ Bt, int N, int K, int kc,
    u16* __restrict__ out16, u16* __restrict__ vt, u16* __restrict__ part) {
  __shared__ __align__(16) u16 As[3][128 * 32];
  __shared__ __align__(16) u16 Bs[3][128 * 32];
  int tid = threadIdx.x;
  int w = tid >> 6, lane = tid & 63;
  int quad = lane >> 4, l15 = lane & 15;
  int wr = w >> 1, wc = w & 1;

  int bid = blockIdx.x;
  int xcd = bid & 7, s = bid >> 3;
  int nn = N >> 7;
  int bx, by, kz;
  if (MODE == 0) {
    int nl = nn >> 3;          // n-tiles per XCD
    by = xcd * nl + s % nl;
    int r = s / nl;
    bx = r & 15;               // nm = 16
    kz = r >> 4;
  } else {
    bx = xcd * 2 + (s & 1);    // m-tiles per XCD = 2
    int r = s >> 1;
    by = r % nn;
    kz = r / nn;
  }
  int m0 = bx * 128, n0 = by * 128;

  f32x4 acc[4][4] = {};

  int lr = lane >> 2, lc = (lane & 3) * 8;
  const u16* Ak = A + (long)(m0 + w * 32 + lr) * K + lc + (long)kz * kc;
  const u16* A2k = Ak + (long)16 * K;
  const u16* Bk = Bt + (long)(n0 + w * 32 + lr) * K + lc + (long)kz * kc;
  const u16* B2k = Bk + (long)16 * K;
  u16* Aw[3] = {As[0] + w * 1024, As[1] + w * 1024, As[2] + w * 1024};
  u16* Bw[3] = {Bs[0] + w * 1024, Bs[1] + w * 1024, Bs[2] + w * 1024};

  int niter = kc >> 5;

  // prologue: issue tiles 0 and 1 (4 loads per tile per thread)
  gload_lds16(Ak, Aw[0]);
  gload_lds16(A2k, Aw[0] + 512);
  gload_lds16(Bk, Bw[0]);
  gload_lds16(B2k, Bw[0] + 512);
  gload_lds16(Ak + 32, Aw[1]);
  gload_lds16(A2k + 32, Aw[1] + 512);
  gload_lds16(Bk + 32, Bw[1]);
  gload_lds16(B2k + 32, Bw[1] + 512);

  int cb = 0;
  for (int k = 0; k < niter; ++k) {
    if (k + 2 < niter) {
      asm volatile("s_waitcnt vmcnt(4)\n\ts_barrier" ::: "memory");
      int pb = (cb == 0) ? 2 : cb - 1;
      int off = (k + 2) * 32;
      gload_lds16(Ak + off, Aw[pb]);
      gload_lds16(A2k + off, Aw[pb] + 512);
      gload_lds16(Bk + off, Bw[pb]);
      gload_lds16(B2k + off, Bw[pb] + 512);
    } else {
      asm volatile("s_waitcnt vmcnt(0)\n\ts_barrier" ::: "memory");
    }
    const u16* Ab = As[cb];
    const u16* Bb = Bs[cb];
    bf16x8 af[4], bfr[4];
#pragma unroll
    for (int mt = 0; mt < 4; ++mt)
      af[mt] = *(const bf16x8*)(Ab + (wr * 64 + mt * 16 + l15) * 32 + quad * 8);
#pragma unroll
    for (int nt = 0; nt < 4; ++nt)
      bfr[nt] = *(const bf16x8*)(Bb + (wc * 64 + nt * 16 + l15) * 32 + quad * 8);
#pragma unroll
    for (int mt = 0; mt < 4; ++mt)
#pragma unroll
      for (int nt = 0; nt < 4; ++nt)
        acc[mt][nt] = __builtin_amdgcn_mfma_f32_16x16x32_bf16(
            af[mt], bfr[nt], acc[mt][nt], 0, 0, 0);
    cb = (cb == 2) ? 0 : cb + 1;
  }

  bool vblock = (EPI == 0) && (vt != nullptr) && (n0 >= 2048);
  u16* pb = nullptr;
  if (EPI == 4) pb = part + (long)kz * MNQ;
#pragma unroll
  for (int mt = 0; mt < 4; ++mt)
#pragma unroll
    for (int nt = 0; nt < 4; ++nt) {
      int col = n0 + wc * 64 + nt * 16 + l15;
      if (EPI == 0 && vblock) {
        int sc = col - 2048;
        int row0 = m0 + wr * 64 + mt * 16 + quad * 4;
        ushort4 pk = make_ushort4(f2bf(acc[mt][nt][0]), f2bf(acc[mt][nt][1]),
                                  f2bf(acc[mt][nt][2]), f2bf(acc[mt][nt][3]));
        *(ushort4*)(vt + (long)sc * 2048 + row0) = pk;
        continue;
      }
#pragma unroll
      for (int r = 0; r < 4; ++r) {
        int row = m0 + wr * 64 + mt * 16 + quad * 4 + r;
        long idx = (long)row * N + col;
        float v = acc[mt][nt][r];
        if (EPI == 0) {
          out16[idx] = f2bf(v);
        } else if (EPI == 2) {
          out16[idx] = f2bf(v / (1.0f + __expf(-v)));
        } else if (EPI == 4) {
          pb[idx] = f2bf(v);
        }
      }
    }
}

// ---------------- FFN2 split-K reduce (bf16 partials) ----------------
__global__ __launch_bounds__(256) void reduce_ffn2_k(
    const u16* __restrict__ part, const float* __restrict__ resid,
    float* __restrict__ out) {
  long i = ((long)blockIdx.x * 256 + threadIdx.x) * 4;
  float4 r = *(const float4*)(resid + i);
  float4 o = r;
#pragma unroll
  for (int z = 0; z < 4; ++z) {
    ushort4 a = *(const ushort4*)(part + z * MNQ + i);
    o.x += bf2f(a.x); o.y += bf2f(a.y); o.z += bf2f(a.z); o.w += bf2f(a.w);
  }
  *(float4*)(out + i) = o;
}

// ------- split-KV flash attention, S^T trick + XCD-aware head placement -----
// 1-D grid 1280 = 8 XCDs x (2 heads x 80 qtile-chunk pairs): each XCD keeps
// its 2 heads' K/V (~1 MB) resident in its own L2.
#define LSTR 72
__global__ __launch_bounds__(256) void attn_part_k(const u16* __restrict__ QKV,
                                                   const u16* __restrict__ Vt,
                                                   u16* __restrict__ Opart,
                                                   float* __restrict__ lpart) {
  __shared__ __align__(16) u16 Qs[64 * LSTR];  // aliased as P after aq read
  __shared__ __align__(16) u16 Ks[64 * LSTR];
  __shared__ __align__(16) u16 Vs[64 * LSTR];
  __shared__ float lbuf[64];

  int tid = threadIdx.x;
  int w = tid >> 6, lane = tid & 63;
  int quad = lane >> 4, l15 = lane & 15;

  int bid = blockIdx.x;
  int xcd = bid & 7, sg = bid >> 3;
  int h = xcd * 2 + (sg & 1);
  int p = sg >> 1;

  int bx = 0, acc0 = 0;
  while (true) {
    int n = (bx >> 3) + 1;
    if (p < acc0 + n) break;
    acc0 += n;
    ++bx;
  }
  int c = p - acc0;
  int t0 = bx * 64;
  int jstart = c * 8;
  int jend = min(jstart + 8, bx + 1);

#pragma unroll
  for (int pp = 0; pp < 2; ++pp) {
    int idx = pp * 256 + tid;
    int row = idx >> 3, cc = idx & 7;
    *(uint4*)(Qs + row * LSTR + cc * 8) =
        *(const uint4*)(QKV + (long)(t0 + row) * 3072 + h * 64 + cc * 8);
  }
  __syncthreads();
  bf16x8 aq[2];
#pragma unroll
  for (int ks = 0; ks < 2; ++ks)
    aq[ks] = *(const bf16x8*)(Qs + (w * 16 + l15) * LSTR + ks * 32 + quad * 8);

  f32x4 oacc[4] = {};
  float lsum = 0.f;
  int qg = t0 + w * 16 + l15;  // this lane's q for S^T columns

  u16* PsW = Qs + w * (16 * LSTR);

  for (int j = jstart; j < jend; ++j) {
    __syncthreads();
#pragma unroll
    for (int pp = 0; pp < 2; ++pp) {
      int idx = pp * 256 + tid;
      int row = idx >> 3, cc = idx & 7;
      *(uint4*)(Ks + row * LSTR + cc * 8) =
          *(const uint4*)(QKV + (long)(j * 64 + row) * 3072 + 1024 + h * 64 + cc * 8);
      *(uint4*)(Vs + row * LSTR + cc * 8) =
          *(const uint4*)(Vt + (long)h * (64 * 2048) + (long)row * 2048 + j * 64 + cc * 8);
    }
    __syncthreads();

    // S^T[u][q]: A=K (m=u), B=Q (n=q)
    f32x4 sacc[4] = {};
#pragma unroll
    for (int ks = 0; ks < 2; ++ks)
#pragma unroll
      for (int ut = 0; ut < 4; ++ut) {
        bf16x8 kf = *(const bf16x8*)(Ks + (ut * 16 + l15) * LSTR + ks * 32 + quad * 8);
        sacc[ut] = __builtin_amdgcn_mfma_f32_16x16x32_bf16(kf, aq[ks], sacc[ut], 0, 0, 0);
      }

    bool boundary = (j == bx);
#pragma unroll
    for (int ut = 0; ut < 4; ++ut) {
      float pv[4];
#pragma unroll
      for (int r = 0; r < 4; ++r) {
        float v = exp2f(sacc[ut][r] * 0.18033688f);
        if (boundary) {
          int u = j * 64 + ut * 16 + quad * 4 + r;
          if (u > qg) v = 0.f;
        }
        pv[r] = v;
        lsum += v;
      }
      ushort4 pk = make_ushort4(f2bf(pv[0]), f2bf(pv[1]), f2bf(pv[2]), f2bf(pv[3]));
      *(ushort4*)(PsW + l15 * LSTR + ut * 16 + quad * 4) = pk;
    }
    asm volatile("s_waitcnt lgkmcnt(0)" ::: "memory");
    // PV: A=P[q][u] (rows q=l15), B=V^T[d][u]
#pragma unroll
    for (int ks = 0; ks < 2; ++ks) {
      bf16x8 pf = *(const bf16x8*)(PsW + l15 * LSTR + ks * 32 + quad * 8);
#pragma unroll
      for (int ct = 0; ct < 4; ++ct) {
        bf16x8 vf = *(const bf16x8*)(Vs + (ct * 16 + l15) * LSTR + ks * 32 + quad * 8);
        oacc[ct] = __builtin_amdgcn_mfma_f32_16x16x32_bf16(pf, vf, oacc[ct], 0, 0, 0);
      }
    }
  }

  // full l(q=w*16+l15): sum over the 4 quads
  lsum += __shfl_xor(lsum, 16, 64);
  lsum += __shfl_xor(lsum, 32, 64);
  if (quad == 0) lbuf[w * 16 + l15] = 1.0f / lsum;
  asm volatile("s_waitcnt lgkmcnt(0)" ::: "memory");

  long slot = (long)p * 16 + h;
  float inv[4];
#pragma unroll
  for (int r = 0; r < 4; ++r) inv[r] = lbuf[w * 16 + quad * 4 + r];
  u16* Ob = Opart + slot * 4096;
#pragma unroll
  for (int ct = 0; ct < 4; ++ct)
#pragma unroll
    for (int r = 0; r < 4; ++r)
      Ob[(w * 16 + quad * 4 + r) * 64 + ct * 16 + l15] = f2bf(oacc[ct][r] * inv[r]);
  if (quad == 0) lpart[slot * 64 + w * 16 + l15] = lsum;
}

// ---------------- combine partials (exact: sum O_c / sum l_c) ----------------
__global__ __launch_bounds__(256) void attn_combine_k(
    const u16* __restrict__ Opart, const float* __restrict__ lpart,
    u16* __restrict__ out) {
  int bx = blockIdx.x, h = blockIdx.y;
  int g = bx >> 3;
  int p0 = 4 * g * (g + 1) + (bx - 8 * g) * (g + 1);
  int nc = g + 1;
  int tid = threadIdx.x;
  int row = tid >> 2, c4 = (tid & 3) * 16;

  float lv[4];
  float wsum = 0.f;
  for (int cidx = 0; cidx < nc; ++cidx) {
    long slot = (long)(p0 + cidx) * 16 + h;
    lv[cidx] = lpart[slot * 64 + row];
    wsum += lv[cidx];
  }
  float rinv = 1.0f / wsum;

  float o[16];
#pragma unroll
  for (int i = 0; i < 16; ++i) o[i] = 0.f;
  for (int cidx = 0; cidx < nc; ++cidx) {
    float wc = lv[cidx] * rinv;
    const u16* Ob = Opart + ((long)(p0 + cidx) * 16 + h) * 4096 + row * 64 + c4;
    bf16x8 a = *(const bf16x8*)Ob;
    bf16x8 b = *(const bf16x8*)(Ob + 8);
#pragma unroll
    for (int i = 0; i < 8; ++i) {
      o[i] += wc * (float)a[i];
      o[8 + i] += wc * (float)b[i];
    }
  }
  u16 ob[16];
#pragma unroll
  for (int i = 0; i < 16; ++i) ob[i] = f2bf(o[i]);
  u16* op = out + (long)(bx * 64 + row) * 1024 + h * 64 + c4;
  *(uint4*)op = *(uint4*)ob;
  *(uint4*)(op + 8) = *(uint4*)(ob + 8);
}

// ---------------- launch ----------------
extern "C" void kernel_launch(void* const* d_in, const int* in_sizes, int n_in,
                              void* d_out, int out_size, void* d_ws, size_t ws_size,
                              hipStream_t stream) {
  const float* x     = (const float*)d_in[0];
  const float* Wq    = (const float*)d_in[1];
  const float* Wk    = (const float*)d_in[2];
  const float* Wv    = (const float*)d_in[3];
  const float* Wproj = (const float*)d_in[4];
  const float* bproj = (const float*)d_in[5];
  const float* W1    = (const float*)d_in[6];
  const float* W2    = (const float*)d_in[7];
  const float* g1    = (const float*)d_in[8];
  const float* g2    = (const float*)d_in[9];

  char* ws = (char*)d_ws;
  u16* QKVwT  = (u16*)(ws);                   // 0..6 MiB
  u16* WprojT = (u16*)(ws + (6ul << 20));     // 6..8
  u16* W1T    = (u16*)(ws + (8ul << 20));     // 8..16
  u16* W2T    = (u16*)(ws + (16ul << 20));    // 16..24 (live thru FFN2)
  u16* xn1    = (u16*)(ws + (24ul << 20));    // 24..28
  u16* QKVb   = (u16*)(ws + (28ul << 20));    // 28..40
  u16* VtB    = (u16*)(ws + (40ul << 20));    // 40..44
  u16* attn   = (u16*)(ws + (44ul << 20));    // 44..48
  float* x1   = (float*)(ws + (48ul << 20));  // 48..56
  u16* xn2    = (u16*)(ws + (56ul << 20));    // 56..60
  u16* hbuf   = (u16*)(ws + (60ul << 20));    // 60..76
  // aliases (dead-region reuse):
  u16* Opart    = (u16*)(ws + (48ul << 20));  // 48..58 (dead before proj_rms)
  float* lpart  = (float*)(ws + (58ul << 20));// 58..58.4
  u16* projp    = (u16*)(ws + (28ul << 20));  // 28..36: 2 x 4 MiB bf16 partials
  u16* ffn2p    = (u16*)(ws + (28ul << 20));  // 28..44 (projp dead by then)
  if (ws_size < (76ul << 20)) return;

  dim3 blk(256);

  prep_k<<<dim3(5120), blk, 0, stream>>>(
      Wq, Wk, Wv, Wproj, W1, W2, x, g1, QKVwT, WprojT, W1T, W2T, xn1);
  // QKV: 384 blocks, partition-n (3 n-tiles/XCD)
  gemm_bt_k<0, 0><<<dim3(384), blk, 0, stream>>>(
      xn1, QKVwT, 3072, 1024, 1024, QKVb, VtB, nullptr);
  attn_part_k<<<dim3(1280), blk, 0, stream>>>(QKVb, VtB, Opart, lpart);
  attn_combine_k<<<dim3(32, 16), blk, 0, stream>>>(Opart, lpart, attn);
  // proj: split-K x2, 256 blocks, partition-n (1 n-tile/XCD)
  gemm_bt_k<4, 0><<<dim3(256), blk, 0, stream>>>(
      attn, WprojT, 1024, 1024, 512, nullptr, nullptr, projp);
  proj_rms_k<<<dim3(2048), blk, 0, stream>>>(projp, bproj, x, g2, x1, xn2);
  // FFN1: 512 blocks, partition-n (4 n-tiles/XCD)
  gemm_bt_k<2, 0><<<dim3(512), blk, 0, stream>>>(
      xn2, W1T, 4096, 1024, 1024, hbuf, nullptr, nullptr);
  // FFN2: split-K x4, 512 blocks, partition-m (A=16MB is the big operand)
  gemm_bt_k<4, 1><<<dim3(512), blk, 0, stream>>>(
      hbuf, W2T, 1024, 4096, 1024, nullptr, nullptr, ffn2p);
  reduce_ffn2_k<<<dim3(2048), blk, 0, stream>>>(ffn2p, x1, (float*)d_out);
}

// Round 11
// 246.930 us; speedup vs baseline: 1.0502x; 1.0325x over previous
//
#include <hip/hip_runtime.h>

typedef unsigned short u16;
typedef unsigned int u32;
typedef __attribute__((ext_vector_type(4))) float f32x4;
typedef __attribute__((ext_vector_type(8))) __bf16 bf16x8;

#define T_SEQ 2048
#define DMODEL 1024
#define NHEAD 16
#define HEADS 64
#define FFDIM 4096
#define MNQ 2097152l  // 2048*1024

__device__ __forceinline__ u16 f2bf(float f) {
  u32 u = __builtin_bit_cast(u32, f);
  u = u + 0x7FFFu + ((u >> 16) & 1u);
  return (u16)(u >> 16);
}
__device__ __forceinline__ float bf2f(u16 h) {
  u32 u = ((u32)h) << 16;
  return __builtin_bit_cast(float, u);
}
__device__ __forceinline__ void gload_lds16(const u16* g, u16* l) {
  __builtin_amdgcn_global_load_lds(
      (const __attribute__((address_space(1))) u32*)g,
      (__attribute__((address_space(3))) u32*)l, 16, 0, 0);
}

// ------------- prep: ALL weight transposes + RMSNorm1 in one launch ----------
__global__ __launch_bounds__(256) void prep_k(
    const float* __restrict__ Wq, const float* __restrict__ Wk,
    const float* __restrict__ Wv, const float* __restrict__ Wproj,
    const float* __restrict__ W1, const float* __restrict__ W2,
    const float* __restrict__ x, const float* __restrict__ g1,
    u16* __restrict__ QKVwT, u16* __restrict__ WprojT,
    u16* __restrict__ W1T, u16* __restrict__ W2T, u16* __restrict__ xn1) {
  __shared__ u16 tile[64 * 66];
  __shared__ float wsum[4];
  int bid = blockIdx.x;
  int tid = threadIdx.x;
  if (bid >= 3072) {
    int row = bid - 3072;
    const float4* xr = (const float4*)(x + (long)row * DMODEL);
    float4 v = xr[tid];
    float ss = v.x * v.x + v.y * v.y + v.z * v.z + v.w * v.w;
#pragma unroll
    for (int off = 32; off >= 1; off >>= 1) ss += __shfl_xor(ss, off, 64);
    if ((tid & 63) == 0) wsum[tid >> 6] = ss;
    __syncthreads();
    float tot = wsum[0] + wsum[1] + wsum[2] + wsum[3];
    float rms = rsqrtf(tot * (1.0f / DMODEL) + 1e-6f);
    float4 gv = ((const float4*)g1)[tid];
    ushort4 o4 = make_ushort4(f2bf(v.x * rms * gv.x), f2bf(v.y * rms * gv.y),
                              f2bf(v.z * rms * gv.z), f2bf(v.w * rms * gv.w));
    ((ushort4*)(xn1 + (long)row * DMODEL))[tid] = o4;
    return;
  }
  const float* in;
  u16* out;
  long ldin, ldout;
  int r0, c0;
  if (bid < 768) {
    int z = bid >> 4, xi = bid & 15;
    int wsel = z >> 4, h = z & 15;
    in = (wsel == 0 ? Wq : (wsel == 1 ? Wk : Wv)) + (long)h * 65536;
    out = QKVwT + (long)wsel * 1048576 + (long)h * 65536;
    ldin = 64; ldout = 1024;
    r0 = xi * 64; c0 = 0;
  } else if (bid < 1024) {
    int b = bid - 768;
    in = Wproj; out = WprojT; ldin = 1024; ldout = 1024;
    r0 = (b >> 4) * 64; c0 = (b & 15) * 64;
  } else if (bid < 2048) {
    int b = bid - 1024;
    in = W1; out = W1T; ldin = 4096; ldout = 1024;
    r0 = (b & 15) * 64; c0 = (b >> 4) * 64;
  } else {
    int b = bid - 2048;
    in = W2; out = W2T; ldin = 1024; ldout = 4096;
    r0 = (b >> 4) * 64; c0 = (b & 15) * 64;
  }
#pragma unroll
  for (int p = 0; p < 16; ++p) {
    int idx = p * 256 + tid;
    int r = idx >> 6, c = idx & 63;
    tile[c * 66 + r] = f2bf(in[(long)(r0 + r) * ldin + c0 + c]);
  }
  __syncthreads();
#pragma unroll
  for (int p = 0; p < 16; ++p) {
    int idx = p * 256 + tid;
    int c = idx >> 6, r = idx & 63;
    out[(long)(c0 + c) * ldout + r0 + r] = tile[c * 66 + r];
  }
}

// ---- fused: proj split-K(x2, bf16 partials) reduce -> x1, RMSNorm -> xn2 ----
__global__ __launch_bounds__(256) void proj_rms_k(
    const u16* __restrict__ part, const float* __restrict__ bias,
    const float* __restrict__ resid, const float* __restrict__ g,
    float* __restrict__ x1, u16* __restrict__ xn2) {
  int row = blockIdx.x;
  int tid = threadIdx.x;
  long i = (long)row * DMODEL + tid * 4;
  float4 r = *(const float4*)(resid + i);
  float4 bi = *(const float4*)(bias + tid * 4);
  float4 v;
  v.x = r.x + bi.x; v.y = r.y + bi.y; v.z = r.z + bi.z; v.w = r.w + bi.w;
#pragma unroll
  for (int z = 0; z < 2; ++z) {
    ushort4 a = *(const ushort4*)(part + z * MNQ + i);
    v.x += bf2f(a.x); v.y += bf2f(a.y); v.z += bf2f(a.z); v.w += bf2f(a.w);
  }
  *(float4*)(x1 + i) = v;
  float ss = v.x * v.x + v.y * v.y + v.z * v.z + v.w * v.w;
#pragma unroll
  for (int off = 32; off >= 1; off >>= 1) ss += __shfl_xor(ss, off, 64);
  __shared__ float wsum[4];
  if ((tid & 63) == 0) wsum[tid >> 6] = ss;
  __syncthreads();
  float tot = wsum[0] + wsum[1] + wsum[2] + wsum[3];
  float rms = rsqrtf(tot * (1.0f / DMODEL) + 1e-6f);
  float4 gv = ((const float4*)g)[tid];
  ushort4 o4 = make_ushort4(f2bf(v.x * rms * gv.x), f2bf(v.y * rms * gv.y),
                            f2bf(v.z * rms * gv.z), f2bf(v.w * rms * gv.w));
  ((ushort4*)(xn2 + (long)row * DMODEL))[tid] = o4;
}

// ---------------- GEMM: C[M,N] = A[M,K] * Bt[N,K]^T, bf16 in, fp32 acc ------
// 128x128 tile, 3-stage global_load_lds pipeline. NITER is compile-time ->
// fully unrolled K-loop with static buffer indices (compiler-global schedule).
// XCD-aware 1-D swizzle (xcd = bid&7). MODE 0: partition n; MODE 1: partition m.
// EPI 0: bf16 (+V-transpose cols>=2048). 2: silu->bf16. 4: bf16 split-K partial
// (pb = (kz<4?p0:p1) + (kz&3)*MNQ).
template <int EPI, int MODE, int NITER>
__global__ __launch_bounds__(256, 3) void gemm_bt_k(
    const u16* __restrict__ A, const u16* __restrict__ Bt, int N,
    u16* __restrict__ out16, u16* __restrict__ vt,
    u16* __restrict__ p0, u16* __restrict__ p1) {
  __shared__ __align__(16) u16 As[3][128 * 32];
  __shared__ __align__(16) u16 Bs[3][128 * 32];
  const int K = 1024 * ((EPI == 4 && MODE == 1) ? 4 : 1);  // FFN2 has K=4096
  const int kc = NITER * 32;
  int tid = threadIdx.x;
  int w = tid >> 6, lane = tid & 63;
  int quad = lane >> 4, l15 = lane & 15;
  int wr = w >> 1, wc = w & 1;

  int bid = blockIdx.x;
  int xcd = bid & 7, s = bid >> 3;
  int nn = N >> 7;
  int bx, by, kz;
  if (MODE == 0) {
    int nl = nn >> 3;
    by = xcd * nl + s % nl;
    int r = s / nl;
    bx = r & 15;
    kz = r >> 4;
  } else {
    bx = xcd * 2 + (s & 1);
    int r = s >> 1;
    by = r % nn;
    kz = r / nn;
  }
  int m0 = bx * 128, n0 = by * 128;

  f32x4 acc[4][4] = {};

  int lr = lane >> 2, lc = (lane & 3) * 8;
  const u16* Ak = A + (long)(m0 + w * 32 + lr) * K + lc + (long)kz * kc;
  const u16* A2k = Ak + (long)16 * K;
  const u16* Bk = Bt + (long)(n0 + w * 32 + lr) * K + lc + (long)kz * kc;
  const u16* B2k = Bk + (long)16 * K;

  // prologue: issue tiles 0 and 1 (4 loads per tile per thread)
  gload_lds16(Ak, As[0] + w * 1024);
  gload_lds16(A2k, As[0] + w * 1024 + 512);
  gload_lds16(Bk, Bs[0] + w * 1024);
  gload_lds16(B2k, Bs[0] + w * 1024 + 512);
  gload_lds16(Ak + 32, As[1] + w * 1024);
  gload_lds16(A2k + 32, As[1] + w * 1024 + 512);
  gload_lds16(Bk + 32, Bs[1] + w * 1024);
  gload_lds16(B2k + 32, Bs[1] + w * 1024 + 512);

#pragma unroll
  for (int k = 0; k < NITER; ++k) {
    const int cb = k % 3;
    if (k + 2 < NITER) {
      asm volatile("s_waitcnt vmcnt(4)\n\ts_barrier" ::: "memory");
      const int pb = (k + 2) % 3;
      const int off = (k + 2) * 32;
      gload_lds16(Ak + off, As[pb] + w * 1024);
      gload_lds16(A2k + off, As[pb] + w * 1024 + 512);
      gload_lds16(Bk + off, Bs[pb] + w * 1024);
      gload_lds16(B2k + off, Bs[pb] + w * 1024 + 512);
    } else {
      asm volatile("s_waitcnt vmcnt(0)\n\ts_barrier" ::: "memory");
    }
    const u16* Ab = As[cb];
    const u16* Bb = Bs[cb];
    bf16x8 af[4], bfr[4];
#pragma unroll
    for (int mt = 0; mt < 4; ++mt)
      af[mt] = *(const bf16x8*)(Ab + (wr * 64 + mt * 16 + l15) * 32 + quad * 8);
#pragma unroll
    for (int nt = 0; nt < 4; ++nt)
      bfr[nt] = *(const bf16x8*)(Bb + (wc * 64 + nt * 16 + l15) * 32 + quad * 8);
#pragma unroll
    for (int mt = 0; mt < 4; ++mt)
#pragma unroll
      for (int nt = 0; nt < 4; ++nt)
        acc[mt][nt] = __builtin_amdgcn_mfma_f32_16x16x32_bf16(
            af[mt], bfr[nt], acc[mt][nt], 0, 0, 0);
  }

  bool vblock = (EPI == 0) && (vt != nullptr) && (n0 >= 2048);
  u16* pb = nullptr;
  if (EPI == 4) pb = (kz < 4 ? p0 : p1) + (long)(kz & 3) * MNQ;
#pragma unroll
  for (int mt = 0; mt < 4; ++mt)
#pragma unroll
    for (int nt = 0; nt < 4; ++nt) {
      int col = n0 + wc * 64 + nt * 16 + l15;
      if (EPI == 0 && vblock) {
        int sc = col - 2048;
        int row0 = m0 + wr * 64 + mt * 16 + quad * 4;
        ushort4 pk = make_ushort4(f2bf(acc[mt][nt][0]), f2bf(acc[mt][nt][1]),
                                  f2bf(acc[mt][nt][2]), f2bf(acc[mt][nt][3]));
        *(ushort4*)(vt + (long)sc * 2048 + row0) = pk;
        continue;
      }
#pragma unroll
      for (int r = 0; r < 4; ++r) {
        int row = m0 + wr * 64 + mt * 16 + quad * 4 + r;
        long idx = (long)row * N + col;
        float v = acc[mt][nt][r];
        if (EPI == 0) {
          out16[idx] = f2bf(v);
        } else if (EPI == 2) {
          out16[idx] = f2bf(v / (1.0f + __expf(-v)));
        } else if (EPI == 4) {
          pb[idx] = f2bf(v);
        }
      }
    }
}

// ---------------- FFN2 split-K(x8) reduce (bf16 partials) ----------------
__global__ __launch_bounds__(256) void reduce_ffn2_k(
    const u16* __restrict__ p0, const u16* __restrict__ p1,
    const float* __restrict__ resid, float* __restrict__ out) {
  long i = ((long)blockIdx.x * 256 + threadIdx.x) * 4;
  float4 r = *(const float4*)(resid + i);
  float4 o = r;
#pragma unroll
  for (int z = 0; z < 4; ++z) {
    ushort4 a = *(const ushort4*)(p0 + z * MNQ + i);
    ushort4 b = *(const ushort4*)(p1 + z * MNQ + i);
    o.x += bf2f(a.x) + bf2f(b.x);
    o.y += bf2f(a.y) + bf2f(b.y);
    o.z += bf2f(a.z) + bf2f(b.z);
    o.w += bf2f(a.w) + bf2f(b.w);
  }
  *(float4*)(out + i) = o;
}

// ------- split-KV flash attention, S^T trick + XCD-aware head placement -----
// Single-chunk q-tiles (bx<8) write normalized output directly to attn.
#define LSTR 72
__global__ __launch_bounds__(256) void attn_part_k(const u16* __restrict__ QKV,
                                                   const u16* __restrict__ Vt,
                                                   u16* __restrict__ Opart,
                                                   float* __restrict__ lpart,
                                                   u16* __restrict__ attn) {
  __shared__ __align__(16) u16 Qs[64 * LSTR];  // aliased as P after aq read
  __shared__ __align__(16) u16 Ks[64 * LSTR];
  __shared__ __align__(16) u16 Vs[64 * LSTR];
  __shared__ float lbuf[64];

  int tid = threadIdx.x;
  int w = tid >> 6, lane = tid & 63;
  int quad = lane >> 4, l15 = lane & 15;

  int bid = blockIdx.x;
  int xcd = bid & 7, sg = bid >> 3;
  int h = xcd * 2 + (sg & 1);
  int p = sg >> 1;

  int bx = 0, acc0 = 0;
  while (true) {
    int n = (bx >> 3) + 1;
    if (p < acc0 + n) break;
    acc0 += n;
    ++bx;
  }
  int c = p - acc0;
  int t0 = bx * 64;
  int jstart = c * 8;
  int jend = min(jstart + 8, bx + 1);

#pragma unroll
  for (int pp = 0; pp < 2; ++pp) {
    int idx = pp * 256 + tid;
    int row = idx >> 3, cc = idx & 7;
    *(uint4*)(Qs + row * LSTR + cc * 8) =
        *(const uint4*)(QKV + (long)(t0 + row) * 3072 + h * 64 + cc * 8);
  }
  __syncthreads();
  bf16x8 aq[2];
#pragma unroll
  for (int ks = 0; ks < 2; ++ks)
    aq[ks] = *(const bf16x8*)(Qs + (w * 16 + l15) * LSTR + ks * 32 + quad * 8);

  f32x4 oacc[4] = {};
  float lsum = 0.f;
  int qg = t0 + w * 16 + l15;  // this lane's q for S^T columns

  u16* PsW = Qs + w * (16 * LSTR);

  for (int j = jstart; j < jend; ++j) {
    __syncthreads();
#pragma unroll
    for (int pp = 0; pp < 2; ++pp) {
      int idx = pp * 256 + tid;
      int row = idx >> 3, cc = idx & 7;
      *(uint4*)(Ks + row * LSTR + cc * 8) =
          *(const uint4*)(QKV + (long)(j * 64 + row) * 3072 + 1024 + h * 64 + cc * 8);
      *(uint4*)(Vs + row * LSTR + cc * 8) =
          *(const uint4*)(Vt + (long)h * (64 * 2048) + (long)row * 2048 + j * 64 + cc * 8);
    }
    __syncthreads();

    // S^T[u][q]: A=K (m=u), B=Q (n=q)
    f32x4 sacc[4] = {};
#pragma unroll
    for (int ks = 0; ks < 2; ++ks)
#pragma unroll
      for (int ut = 0; ut < 4; ++ut) {
        bf16x8 kf = *(const bf16x8*)(Ks + (ut * 16 + l15) * LSTR + ks * 32 + quad * 8);
        sacc[ut] = __builtin_amdgcn_mfma_f32_16x16x32_bf16(kf, aq[ks], sacc[ut], 0, 0, 0);
      }

    bool boundary = (j == bx);
#pragma unroll
    for (int ut = 0; ut < 4; ++ut) {
      float pv[4];
#pragma unroll
      for (int r = 0; r < 4; ++r) {
        float v = exp2f(sacc[ut][r] * 0.18033688f);
        if (boundary) {
          int u = j * 64 + ut * 16 + quad * 4 + r;
          if (u > qg) v = 0.f;
        }
        pv[r] = v;
        lsum += v;
      }
      ushort4 pk = make_ushort4(f2bf(pv[0]), f2bf(pv[1]), f2bf(pv[2]), f2bf(pv[3]));
      *(ushort4*)(PsW + l15 * LSTR + ut * 16 + quad * 4) = pk;
    }
    asm volatile("s_waitcnt lgkmcnt(0)" ::: "memory");
    // PV: A=P[q][u] (rows q=l15), B=V^T[d][u]
#pragma unroll
    for (int ks = 0; ks < 2; ++ks) {
      bf16x8 pf = *(const bf16x8*)(PsW + l15 * LSTR + ks * 32 + quad * 8);
#pragma unroll
      for (int ct = 0; ct < 4; ++ct) {
        bf16x8 vf = *(const bf16x8*)(Vs + (ct * 16 + l15) * LSTR + ks * 32 + quad * 8);
        oacc[ct] = __builtin_amdgcn_mfma_f32_16x16x32_bf16(pf, vf, oacc[ct], 0, 0, 0);
      }
    }
  }

  // full l(q=w*16+l15): sum over the 4 quads
  lsum += __shfl_xor(lsum, 16, 64);
  lsum += __shfl_xor(lsum, 32, 64);
  if (quad == 0) lbuf[w * 16 + l15] = 1.0f / lsum;
  asm volatile("s_waitcnt lgkmcnt(0)" ::: "memory");

  float inv[4];
#pragma unroll
  for (int r = 0; r < 4; ++r) inv[r] = lbuf[w * 16 + quad * 4 + r];

  if (bx < 8) {
    // single chunk: write normalized output directly
#pragma unroll
    for (int ct = 0; ct < 4; ++ct)
#pragma unroll
      for (int r = 0; r < 4; ++r)
        attn[(long)(t0 + w * 16 + quad * 4 + r) * 1024 + h * 64 + ct * 16 + l15] =
            f2bf(oacc[ct][r] * inv[r]);
    return;
  }
  long slot = (long)p * 16 + h;
  u16* Ob = Opart + slot * 4096;
#pragma unroll
  for (int ct = 0; ct < 4; ++ct)
#pragma unroll
    for (int r = 0; r < 4; ++r)
      Ob[(w * 16 + quad * 4 + r) * 64 + ct * 16 + l15] = f2bf(oacc[ct][r] * inv[r]);
  if (quad == 0) lpart[slot * 64 + w * 16 + l15] = lsum;
}

// ---------------- combine partials (bx >= 8 only) ----------------
__global__ __launch_bounds__(256) void attn_combine_k(
    const u16* __restrict__ Opart, const float* __restrict__ lpart,
    u16* __restrict__ out) {
  int bx = blockIdx.x + 8, h = blockIdx.y;
  int g = bx >> 3;
  int p0 = 4 * g * (g + 1) + (bx - 8 * g) * (g + 1);
  int nc = g + 1;
  int tid = threadIdx.x;
  int row = tid >> 2, c4 = (tid & 3) * 16;

  float lv[4];
  float wsum = 0.f;
  for (int cidx = 0; cidx < nc; ++cidx) {
    long slot = (long)(p0 + cidx) * 16 + h;
    lv[cidx] = lpart[slot * 64 + row];
    wsum += lv[cidx];
  }
  float rinv = 1.0f / wsum;

  float o[16];
#pragma unroll
  for (int i = 0; i < 16; ++i) o[i] = 0.f;
  for (int cidx = 0; cidx < nc; ++cidx) {
    float wc = lv[cidx] * rinv;
    const u16* Ob = Opart + ((long)(p0 + cidx) * 16 + h) * 4096 + row * 64 + c4;
    bf16x8 a = *(const bf16x8*)Ob;
    bf16x8 b = *(const bf16x8*)(Ob + 8);
#pragma unroll
    for (int i = 0; i < 8; ++i) {
      o[i] += wc * (float)a[i];
      o[8 + i] += wc * (float)b[i];
    }
  }
  u16 ob[16];
#pragma unroll
  for (int i = 0; i < 16; ++i) ob[i] = f2bf(o[i]);
  u16* op = out + (long)(bx * 64 + row) * 1024 + h * 64 + c4;
  *(uint4*)op = *(uint4*)ob;
  *(uint4*)(op + 8) = *(uint4*)(ob + 8);
}

// ---------------- launch ----------------
extern "C" void kernel_launch(void* const* d_in, const int* in_sizes, int n_in,
                              void* d_out, int out_size, void* d_ws, size_t ws_size,
                              hipStream_t stream) {
  const float* x     = (const float*)d_in[0];
  const float* Wq    = (const float*)d_in[1];
  const float* Wk    = (const float*)d_in[2];
  const float* Wv    = (const float*)d_in[3];
  const float* Wproj = (const float*)d_in[4];
  const float* bproj = (const float*)d_in[5];
  const float* W1    = (const float*)d_in[6];
  const float* W2    = (const float*)d_in[7];
  const float* g1    = (const float*)d_in[8];
  const float* g2    = (const float*)d_in[9];

  char* ws = (char*)d_ws;
  u16* QKVwT  = (u16*)(ws);                   // 0..6 MiB
  u16* WprojT = (u16*)(ws + (6ul << 20));     // 6..8
  u16* W1T    = (u16*)(ws + (8ul << 20));     // 8..16
  u16* W2T    = (u16*)(ws + (16ul << 20));    // 16..24 (live thru FFN2)
  u16* xn1    = (u16*)(ws + (24ul << 20));    // 24..28
  u16* QKVb   = (u16*)(ws + (28ul << 20));    // 28..40
  u16* VtB    = (u16*)(ws + (40ul << 20));    // 40..44
  u16* attn   = (u16*)(ws + (44ul << 20));    // 44..48
  float* x1   = (float*)(ws + (48ul << 20));  // 48..56
  u16* xn2    = (u16*)(ws + (56ul << 20));    // 56..60
  u16* hbuf   = (u16*)(ws + (60ul << 20));    // 60..76
  // aliases (dead-region reuse):
  u16* Opart    = (u16*)(ws + (48ul << 20));  // 48..58 (dead before proj_rms)
  float* lpart  = (float*)(ws + (58ul << 20));// 58..58.4
  u16* projp    = (u16*)(ws + (28ul << 20));  // 28..36: 2 x 4 MiB bf16 partials
  u16* ffn2pA   = (u16*)(ws + (28ul << 20));  // 28..44: kz 0..3 (QKVb/VtB dead)
  u16* ffn2pB   = (u16*)(ws);                 // 0..16: kz 4..7 (QKV/proj/W1 weights dead)
  if (ws_size < (76ul << 20)) return;

  dim3 blk(256);

  prep_k<<<dim3(5120), blk, 0, stream>>>(
      Wq, Wk, Wv, Wproj, W1, W2, x, g1, QKVwT, WprojT, W1T, W2T, xn1);
  // QKV: 384 blocks, partition-n (3 n-tiles/XCD), K=1024 (NITER=32)
  gemm_bt_k<0, 0, 32><<<dim3(384), blk, 0, stream>>>(
      xn1, QKVwT, 3072, QKVb, VtB, nullptr, nullptr);
  attn_part_k<<<dim3(1280), blk, 0, stream>>>(QKVb, VtB, Opart, lpart, attn);
  attn_combine_k<<<dim3(24, 16), blk, 0, stream>>>(Opart, lpart, attn);
  // proj: split-K x2 (kc=512, NITER=16), 256 blocks, partition-n
  gemm_bt_k<4, 0, 16><<<dim3(256), blk, 0, stream>>>(
      attn, WprojT, 1024, nullptr, nullptr, projp, nullptr);
  proj_rms_k<<<dim3(2048), blk, 0, stream>>>(projp, bproj, x, g2, x1, xn2);
  // FFN1: 512 blocks, partition-n (4 n-tiles/XCD), K=1024 (NITER=32)
  gemm_bt_k<2, 0, 32><<<dim3(512), blk, 0, stream>>>(
      xn2, W1T, 4096, hbuf, nullptr, nullptr, nullptr);
  // FFN2: split-K x8 (kc=512, NITER=16), 1024 blocks (3/CU), partition-m
  gemm_bt_k<4, 1, 16><<<dim3(1024), blk, 0, stream>>>(
      hbuf, W2T, 1024, nullptr, nullptr, ffn2pA, ffn2pB);
  reduce_ffn2_k<<<dim3(2048), blk, 0, stream>>>(ffn2pA, ffn2pB, x1, (float*)d_out);
}